// Round 4
// baseline (213.128 us; speedup 1.0000x reference)
//
#include <hip/hip_runtime.h>

// Problem geometry (fixed by setup_inputs)
constexpr int N_ = 8, C_ = 8, H_ = 1024, W_ = 1024;

// k1 tiling: 64x32 output tile, blur halo 2, staged rows 36
constexpr int TW = 64, TH = 32, R_ = 36;
constexpr int THREADS = 256;

// k2 tiling (sobel, halo 1)
constexpr int T2W = 64, T2H = 16;
constexpr int T2SX = T2W + 2, T2SY = T2H + 2;

// Gaussian kernel: cv2.getGaussianKernel(5, 2), normalized
constexpr float G0_ = 0.15246914f;
constexpr float G1_ = 0.22184130f;
constexpr float G2_ = 0.25137912f;

#define GLOAD_LDS16(gp, lp) __builtin_amdgcn_global_load_lds( \
    (const __attribute__((address_space(1))) void*)(gp),      \
    (__attribute__((address_space(3))) void*)(lp), 16, 0, 0)
#define GLOAD_LDS4(gp, lp) __builtin_amdgcn_global_load_lds(  \
    (const __attribute__((address_space(1))) void*)(gp),      \
    (__attribute__((address_space(3))) void*)(lp), 4, 0, 0)

__device__ __forceinline__ float block_reduce(float v, float* red4) {
    #pragma unroll
    for (int off = 32; off > 0; off >>= 1) v += __shfl_down(v, off);
    const int lane = threadIdx.x & 63, wid = threadIdx.x >> 6;
    if (lane == 0) red4[wid] = v;
    __syncthreads();
    float s = 0.f;
    if (threadIdx.x == 0) s = red4[0] + red4[1] + red4[2] + red4[3];
    __syncthreads();
    return s;
}

// branchless reflect-101 for H=W=1024 range [-2, 1057]
__device__ __forceinline__ int refl(int y) {
    int a = (y < 0) ? -y : y;
    int b = 2046 - a;
    return (a < b) ? a : b;
}

__global__ __launch_bounds__(THREADS)
void k1_blur_sums(const float* __restrict__ outp,
                  const float* __restrict__ refp,
                  const float* __restrict__ msp,
                  float* __restrict__ o2p,
                  double* __restrict__ part_ms,
                  double* __restrict__ part_ref)
{
    __shared__ float til[2][R_ * TW];   // linear [36][64] per buffer (global_load_lds dest)
    __shared__ float hal[2][192];       // x-halo: [r][4] = cols {-2,-1,64,65}, slots 144..191 junk
    __shared__ float red4[4];

    const int t = threadIdx.x, lane = t & 63, wv = t >> 6;
    const int tx = blockIdx.x, ty = blockIdx.y, n = blockIdx.z;
    const int x0 = tx * TW, y0 = ty * TH;

    const int pr  = (t >> 4) << 1;
    const int col = (t & 15) << 2;

    // async-stage channel c into buffer buf — EXACTLY 3 gload_lds per wave
    auto stage = [&](int c, int buf) {
        const float* plane = outp + ((size_t)(n * C_ + c) << 20);
        for (int wl = wv; wl < 9; wl += 4) {          // wv=0:{0,4,8}; wv>0: 2 loads
            int s  = (wl << 6) + lane;                // f4-slot 0..575
            int gy = refl(y0 + (s >> 4) - 2);
            const float* src = plane + ((size_t)gy << 10) + (x0 + ((s & 15) << 2));
            GLOAD_LDS16(src, &til[buf][wl << 8]);
        }
        if (wv > 0) {                                  // wv>0: +1 halo load = 3 total
            int s = ((wv - 1) << 6) + lane;            // 0..191 (144 real)
            int r = (s >> 2) > 35 ? 35 : (s >> 2);
            int cdx = s & 3;
            int gy = refl(y0 + r - 2);
            int gx = refl(x0 + ((cdx < 2) ? cdx - 2 : cdx + 62));
            const float* src = plane + ((size_t)gy << 10) + gx;
            GLOAD_LDS4(src, &hal[buf][(wv - 1) << 6]);
        }
    };

    float accMs = 0.f, accRef = 0.f;
    float4 cs0 = {0,0,0,0}, cs1 = {0,0,0,0};

    stage(0, 0);                                       // 3 VMEM in flight

    for (int c = 0; c < C_; ++c) {
        const int cur = c & 1;

        // 1. issue ms/ref loads (4 VMEM)
        const size_t gidx = ((size_t)(n * C_ + c) * H_ + (y0 + pr)) * W_ + x0 + col;
        float4 m0 = *(const float4*)(msp + gidx);
        float4 m1 = *(const float4*)(msp + gidx + W_);
        float4 r0 = *(const float4*)(refp + gidx);
        float4 r1 = *(const float4*)(refp + gidx + W_);

        // 2. wait own stage(c) (m/r = 4 newest stay in flight)
        asm volatile("s_waitcnt vmcnt(4)" ::: "memory");
        // 3. all waves' stage(c) drained; til[cur] ready; prev reads done
        __builtin_amdgcn_s_barrier();

        // 4. issue stage(c+1) into other buffer (3 VMEM)
        if (c + 1 < C_) stage(c + 1, cur ^ 1);

        // 5. drain m/r; keep stage(c+1) in flight across the whole channel
        asm volatile("s_waitcnt vmcnt(3)" ::: "memory");

        // 6. compute from til[cur]
        const float* T  = &til[cur][0];
        const float* Hh = &hal[cur][0];

        float4 b0 = {0,0,0,0}, b1 = {0,0,0,0};
        float4 o0, o1;

        #pragma unroll
        for (int dr = 0; dr < 6; ++dr) {
            const int r = pr + dr;
            const float* rowp = T + (r << 6);
            const float* lp = (col == 0)  ? (Hh + (r << 2))     : (rowp + col - 2);
            const float* rp = (col == 60) ? (Hh + (r << 2) + 2) : (rowp + col + 4);
            float2 l2 = *(const float2*)lp;
            float4 m4 = *(const float4*)(rowp + col);
            float2 r2 = *(const float2*)rp;
            float s0 = l2.x, s1 = l2.y, s2 = m4.x, s3 = m4.y;
            float s4 = m4.z, s5 = m4.w, s6 = r2.x, s7 = r2.y;
            float4 h;
            h.x = G0_ * (s0 + s4) + G1_ * (s1 + s3) + G2_ * s2;
            h.y = G0_ * (s1 + s5) + G1_ * (s2 + s4) + G2_ * s3;
            h.z = G0_ * (s2 + s6) + G1_ * (s3 + s5) + G2_ * s4;
            h.w = G0_ * (s3 + s7) + G1_ * (s4 + s6) + G2_ * s5;
            const float w0 = (dr == 0 || dr == 4) ? G0_ : (dr == 1 || dr == 3) ? G1_ : (dr == 2) ? G2_ : 0.f;
            const float w1 = (dr == 1 || dr == 5) ? G0_ : (dr == 2 || dr == 4) ? G1_ : (dr == 3) ? G2_ : 0.f;
            if (dr < 5) { b0.x += w0*h.x; b0.y += w0*h.y; b0.z += w0*h.z; b0.w += w0*h.w; }
            if (dr > 0) { b1.x += w1*h.x; b1.y += w1*h.y; b1.z += w1*h.z; b1.w += w1*h.w; }
            if (dr == 2) o0 = m4;
            if (dr == 3) o1 = m4;
        }

        accMs += fabsf(b0.x - m0.x) + fabsf(b0.y - m0.y) + fabsf(b0.z - m0.z) + fabsf(b0.w - m0.w)
               + fabsf(b1.x - m1.x) + fabsf(b1.y - m1.y) + fabsf(b1.z - m1.z) + fabsf(b1.w - m1.w);
        accRef += fabsf(o0.x - r0.x) + fabsf(o0.y - r0.y) + fabsf(o0.z - r0.z) + fabsf(o0.w - r0.w)
                + fabsf(o1.x - r1.x) + fabsf(o1.y - r1.y) + fabsf(o1.z - r1.z) + fabsf(o1.w - r1.w);
        cs0.x += o0.x; cs0.y += o0.y; cs0.z += o0.z; cs0.w += o0.w;
        cs1.x += o1.x; cs1.y += o1.y; cs1.z += o1.z; cs1.w += o1.w;
    }

    {
        const size_t oidx = ((size_t)n * H_ + (y0 + pr)) * W_ + x0 + col;
        float4 w0, w1;
        w0.x = cs0.x * 0.125f; w0.y = cs0.y * 0.125f; w0.z = cs0.z * 0.125f; w0.w = cs0.w * 0.125f;
        w1.x = cs1.x * 0.125f; w1.y = cs1.y * 0.125f; w1.z = cs1.z * 0.125f; w1.w = cs1.w * 0.125f;
        *(float4*)&o2p[oidx] = w0;
        *(float4*)&o2p[oidx + W_] = w1;
    }

    float sMs = block_reduce(accMs, red4);
    float sRef = block_reduce(accRef, red4);
    if (t == 0) {
        const int bid = (n * gridDim.y + ty) * gridDim.x + tx;
        part_ms[bid]  = (double)sMs;
        part_ref[bid] = (double)sRef;
    }
}

__global__ __launch_bounds__(THREADS)
void k2_sobel(const float* __restrict__ pan,
              const float* __restrict__ o2p,
              double* __restrict__ part_pan)
{
    __shared__ float d[T2SY * T2SX];
    __shared__ float red4[4];

    const int t = threadIdx.x;
    const int tx = blockIdx.x, ty = blockIdx.y, n = blockIdx.z;
    const int x0 = tx * T2W, y0 = ty * T2H;
    const size_t base = (size_t)n * (H_ * W_);

    for (int i = t; i < T2SY * T2SX; i += THREADS) {
        int r = i / T2SX, q = i - r * T2SX;
        int gy = y0 + r - 1, gx = x0 + q - 1;
        float v = 0.f;
        if (gy >= 0 && gy < H_ && gx >= 0 && gx < W_) {
            size_t gi = base + (size_t)gy * W_ + gx;
            v = pan[gi] - o2p[gi];
        }
        d[i] = v;
    }
    __syncthreads();

    const int row = (t >> 4) + 1;
    const int colb = ((t & 15) << 2) + 1;
    float acc = 0.f;
    #pragma unroll
    for (int j = 0; j < 4; ++j) {
        const int q = colb + j;
        const float* c0 = &d[(row - 1) * T2SX + q];
        const float* c1 = &d[(row    ) * T2SX + q];
        const float* c2 = &d[(row + 1) * T2SX + q];
        float gx = (c0[1] - c0[-1]) + 2.f * (c1[1] - c1[-1]) + (c2[1] - c2[-1]);
        float gy = (c2[-1] + 2.f * c2[0] + c2[1]) - (c0[-1] + 2.f * c0[0] + c0[1]);
        acc += fabsf(gx) + fabsf(gy);
    }

    float s = block_reduce(acc, red4);
    if (t == 0) {
        const int bid = (n * gridDim.y + ty) * gridDim.x + tx;
        part_pan[bid] = (double)s;
    }
}

__global__ __launch_bounds__(256)
void k3_final(const double* __restrict__ part_ms,
              const double* __restrict__ part_ref,
              const double* __restrict__ part_pan,
              int nb1, int nb2, float* __restrict__ outv)
{
    __shared__ double sMs[256], sRef[256], sPan[256];
    const int t = threadIdx.x;
    double a = 0.0, b = 0.0, c = 0.0;
    for (int i = t; i < nb1; i += 256) {
        a += part_ms[i];
        b += part_ref[i];
    }
    for (int i = t; i < nb2; i += 256) {
        c += part_pan[i];
    }
    sMs[t] = a; sRef[t] = b; sPan[t] = c;
    __syncthreads();
    for (int s = 128; s > 0; s >>= 1) {
        if (t < s) { sMs[t] += sMs[t + s]; sRef[t] += sRef[t + s]; sPan[t] += sPan[t + s]; }
        __syncthreads();
    }
    if (t == 0) {
        const double inv_big = 1.0 / (double)(N_ * C_ * H_ * W_);
        const double inv_pan = 1.0 / (double)(N_ * 1 * H_ * W_);
        double total = sMs[0] * inv_big + sRef[0] * inv_big + sPan[0] * inv_pan;
        outv[0] = (float)total;
    }
}

extern "C" void kernel_launch(void* const* d_in, const int* in_sizes, int n_in,
                              void* d_out, int out_size, void* d_ws, size_t ws_size,
                              hipStream_t stream) {
    const float* refp = (const float*)d_in[0];
    const float* pan  = (const float*)d_in[1];
    const float* msp  = (const float*)d_in[2];
    const float* outp = (const float*)d_in[3];

    const int NB1 = (W_ / TW) * (H_ / TH) * N_;    // 4096
    const int NB2 = (W_ / T2W) * (H_ / T2H) * N_;  // 8192

    char* ws = (char*)d_ws;
    float* o2p = (float*)ws;
    size_t o2p_bytes = (size_t)N_ * H_ * W_ * sizeof(float);
    double* part_ms  = (double*)(ws + o2p_bytes);
    double* part_ref = part_ms + NB1;
    double* part_pan = part_ref + NB1;

    dim3 grid1(W_ / TW, H_ / TH, N_);
    k1_blur_sums<<<grid1, THREADS, 0, stream>>>(outp, refp, msp, o2p, part_ms, part_ref);
    dim3 grid2(W_ / T2W, H_ / T2H, N_);
    k2_sobel<<<grid2, THREADS, 0, stream>>>(pan, o2p, part_pan);
    k3_final<<<1, 256, 0, stream>>>(part_ms, part_ref, part_pan, NB1, NB2, (float*)d_out);
}

// Round 6
// 178.466 us; speedup vs baseline: 1.1942x; 1.1942x over previous
//
#include <hip/hip_runtime.h>

// Problem geometry (fixed by setup_inputs)
constexpr int N_ = 8, C_ = 8, H_ = 1024, W_ = 1024;

// k1 tiling: 256x16 output tile, blur halo 2 -> 20 staged rows
constexpr int TW = 256, TH = 16, R_ = 20;
constexpr int THREADS = 256;

// k2 tiling: 256x16, sobel halo 1 -> 18 staged rows
constexpr int R2_ = 18;

// Gaussian kernel: cv2.getGaussianKernel(5, 2), normalized
constexpr float G0_ = 0.15246914f;
constexpr float G1_ = 0.22184130f;
constexpr float G2_ = 0.25137912f;

#define GLOAD_LDS16(gp, lp) __builtin_amdgcn_global_load_lds( \
    (const __attribute__((address_space(1))) void*)(gp),      \
    (__attribute__((address_space(3))) void*)(lp), 16, 0, 0)
#define GLOAD_LDS4(gp, lp) __builtin_amdgcn_global_load_lds(  \
    (const __attribute__((address_space(1))) void*)(gp),      \
    (__attribute__((address_space(3))) void*)(lp), 4, 0, 0)

__device__ __forceinline__ float block_reduce(float v, float* red4) {
    #pragma unroll
    for (int off = 32; off > 0; off >>= 1) v += __shfl_down(v, off);
    const int lane = threadIdx.x & 63, wid = threadIdx.x >> 6;
    if (lane == 0) red4[wid] = v;
    __syncthreads();
    float s = 0.f;
    if (threadIdx.x == 0) s = red4[0] + red4[1] + red4[2] + red4[3];
    __syncthreads();
    return s;
}

// branchless reflect-101 for H=W=1024, arg range [-2, 1057]
__device__ __forceinline__ int refl(int y) {
    int a = (y < 0) ? -y : y;
    int b = 2046 - a;
    return (a < b) ? a : b;
}

__global__ __launch_bounds__(THREADS)
void k1_blur_sums(const float* __restrict__ outp,
                  const float* __restrict__ refp,
                  const float* __restrict__ msp,
                  float* __restrict__ o2p,
                  double* __restrict__ part_ms,
                  double* __restrict__ part_ref)
{
    __shared__ float til[2][R_ * TW];   // [20][256] per buffer; 1 row = 1 wave gload_lds16
    __shared__ float hal[2][80];        // x-halo: [r][4] = cols {-2,-1,256,257}
    __shared__ float red4[4];

    const int t = threadIdx.x, lane = t & 63, wv = t >> 6;
    const int tx = blockIdx.x, ty = blockIdx.y, n = blockIdx.z;
    const int x0 = tx * TW, y0 = ty * TH;

    // thread strip: cols c0..c0+3, output rows sr0..sr0+3
    const int c0  = (t & 63) << 2;
    const int sr0 = (t >> 6) << 2;

    // stage channel c: interior = 5 full-row 1KB wave-loads; halo = 80 scalars
    auto stage = [&](int c, int buf) {
        const float* plane = outp + ((size_t)(n * C_ + c) << 20);
        #pragma unroll
        for (int k = 0; k < 5; ++k) {
            const int r = wv + (k << 2);               // rows wv, wv+4, ..., wv+16
            const int gy = refl(y0 + r - 2);
            GLOAD_LDS16(plane + ((size_t)gy << 10) + x0 + (lane << 2),
                        &til[buf][r << 8]);
        }
        if (wv == 0 || (wv == 1 && lane < 16)) {       // 80 halo slots
            const int slot = (wv == 0) ? lane : (64 + lane);
            const int r = slot >> 2, cdx = slot & 3;
            const int gy = refl(y0 + r - 2);
            const int gx = refl(x0 + ((cdx < 2) ? cdx - 2 : cdx + 254));
            GLOAD_LDS4(plane + ((size_t)gy << 10) + gx,
                       &hal[buf][(wv == 0) ? 0 : 64]);
        }
    };

    float accMs = 0.f, accRef = 0.f;
    float4 cs4[4] = {{0,0,0,0},{0,0,0,0},{0,0,0,0},{0,0,0,0}};

    stage(0, 0);
    __syncthreads();

    for (int c = 0; c < C_; ++c) {
        const int cur = c & 1;
        if (c + 1 < C_) stage(c + 1, cur ^ 1);

        const float* T  = &til[cur][0];
        const float* Hh = &hal[cur][0];

        // rolling h-blur over 8 staged rows sr0..sr0+7
        float4 hh[8], ctr[4];
        #pragma unroll
        for (int k = 0; k < 8; ++k) {
            const int r = sr0 + k;                     // <= 19
            const float* rowp = T + (r << 8);
            float2 l2 = (c0 == 0)   ? *(const float2*)(Hh + (r << 2))
                                    : *(const float2*)(rowp + c0 - 2);
            float4 m4 = *(const float4*)(rowp + c0);
            float2 r2 = (c0 == 252) ? *(const float2*)(Hh + (r << 2) + 2)
                                    : *(const float2*)(rowp + c0 + 4);
            float4 h;
            h.x = G0_ * (l2.x + m4.z) + G1_ * (l2.y + m4.y) + G2_ * m4.x;
            h.y = G0_ * (l2.y + m4.w) + G1_ * (m4.x + m4.z) + G2_ * m4.y;
            h.z = G0_ * (m4.x + r2.x) + G1_ * (m4.y + m4.w) + G2_ * m4.z;
            h.w = G0_ * (m4.y + r2.y) + G1_ * (m4.z + r2.x) + G2_ * m4.w;
            hh[k] = h;
            if (k >= 2 && k <= 5) ctr[k - 2] = m4;     // raw out at output rows
        }

        // v-blur + losses, 4 output rows
        #pragma unroll
        for (int j = 0; j < 4; ++j) {
            float4 b;
            b.x = G0_*(hh[j].x+hh[j+4].x) + G1_*(hh[j+1].x+hh[j+3].x) + G2_*hh[j+2].x;
            b.y = G0_*(hh[j].y+hh[j+4].y) + G1_*(hh[j+1].y+hh[j+3].y) + G2_*hh[j+2].y;
            b.z = G0_*(hh[j].z+hh[j+4].z) + G1_*(hh[j+1].z+hh[j+3].z) + G2_*hh[j+2].z;
            b.w = G0_*(hh[j].w+hh[j+4].w) + G1_*(hh[j+1].w+hh[j+3].w) + G2_*hh[j+2].w;

            const size_t gidx = ((size_t)(n * C_ + c) * H_ + (y0 + sr0 + j)) * W_ + x0 + c0;
            float4 m = *(const float4*)(msp + gidx);
            float4 rr = *(const float4*)(refp + gidx);
            float4 o = ctr[j];

            accMs  += fabsf(b.x - m.x) + fabsf(b.y - m.y) + fabsf(b.z - m.z) + fabsf(b.w - m.w);
            accRef += fabsf(o.x - rr.x) + fabsf(o.y - rr.y) + fabsf(o.z - rr.z) + fabsf(o.w - rr.w);
            cs4[j].x += o.x; cs4[j].y += o.y; cs4[j].z += o.z; cs4[j].w += o.w;
        }

        __syncthreads();   // til[cur] reads done; stage(c+1) drained
    }

    // out2pan write: 4 rows, 1KB contiguous per wave per row
    #pragma unroll
    for (int j = 0; j < 4; ++j) {
        const size_t oidx = ((size_t)n * H_ + (y0 + sr0 + j)) * W_ + x0 + c0;
        float4 w;
        w.x = cs4[j].x * 0.125f; w.y = cs4[j].y * 0.125f;
        w.z = cs4[j].z * 0.125f; w.w = cs4[j].w * 0.125f;
        *(float4*)&o2p[oidx] = w;
    }

    float sMs = block_reduce(accMs, red4);
    float sRef = block_reduce(accRef, red4);
    if (t == 0) {
        const int bid = (n * gridDim.y + ty) * gridDim.x + tx;
        part_ms[bid]  = (double)sMs;
        part_ref[bid] = (double)sRef;
    }
}

__global__ __launch_bounds__(THREADS)
void k2_sobel(const float* __restrict__ pan,
              const float* __restrict__ o2p,
              double* __restrict__ part_pan)
{
    __shared__ float d[R2_ * 256];   // staged rows = image rows y0-1 .. y0+16
    __shared__ float sd[R2_ * 2];    // side cols: [r][0]=x0-1, [r][1]=x0+256
    __shared__ float red4[4];

    const int t = threadIdx.x;
    const int tx = blockIdx.x, ty = blockIdx.y, n = blockIdx.z;
    const int x0 = tx * TW, y0 = ty * TH;
    const size_t base = (size_t)n * (H_ * W_);

    // interior staging: rows of 1KB (pan & o2p reads both contiguous per wave)
    for (int i = t; i < R2_ * 64; i += THREADS) {
        const int r = i >> 6, cf = (i & 63) << 2;
        const int gy = y0 + r - 1;
        float4 v = {0,0,0,0};
        if (gy >= 0 && gy < H_) {
            const size_t gi = base + ((size_t)gy << 10) + x0 + cf;
            float4 p4 = *(const float4*)(pan + gi);
            float4 q4 = *(const float4*)(o2p + gi);
            v.x = p4.x - q4.x; v.y = p4.y - q4.y; v.z = p4.z - q4.z; v.w = p4.w - q4.w;
        }
        *(float4*)&d[(r << 8) + cf] = v;
    }
    if (t < R2_ * 2) {
        const int r = t >> 1, s = t & 1;
        const int gy = y0 + r - 1;
        const int gx = s ? (x0 + 256) : (x0 - 1);
        float v = 0.f;
        if (gy >= 0 && gy < H_ && gx >= 0 && gx < W_) {
            const size_t gi = base + ((size_t)gy << 10) + gx;
            v = pan[gi] - o2p[gi];
        }
        sd[(r << 1) + s] = v;
    }
    __syncthreads();

    const int c0  = (t & 63) << 2;
    const int sr0 = (t >> 6) << 2;   // thread's staged rows sr0..sr0+5; outputs sr0+1..sr0+4

    float4 hx[6], hs[6];
    #pragma unroll
    for (int k = 0; k < 6; ++k) {
        const int r = sr0 + k;                         // <= 17
        const float* rowp = d + (r << 8);
        float lft = (c0 == 0)   ? sd[r << 1]       : rowp[c0 - 1];
        float4 m4 = *(const float4*)(rowp + c0);
        float rgt = (c0 == 252) ? sd[(r << 1) + 1] : rowp[c0 + 4];
        hx[k].x = m4.y - lft;  hx[k].y = m4.z - m4.x;
        hx[k].z = m4.w - m4.y; hx[k].w = rgt - m4.z;
        hs[k].x = lft + 2.f*m4.x + m4.y;  hs[k].y = m4.x + 2.f*m4.y + m4.z;
        hs[k].z = m4.y + 2.f*m4.z + m4.w; hs[k].w = m4.z + 2.f*m4.w + rgt;
    }

    float acc = 0.f;
    #pragma unroll
    for (int j = 0; j < 4; ++j) {   // output centered at staged row sr0+j+1
        float4 gx4, gy4;
        gx4.x = hx[j].x + 2.f*hx[j+1].x + hx[j+2].x;
        gx4.y = hx[j].y + 2.f*hx[j+1].y + hx[j+2].y;
        gx4.z = hx[j].z + 2.f*hx[j+1].z + hx[j+2].z;
        gx4.w = hx[j].w + 2.f*hx[j+1].w + hx[j+2].w;
        gy4.x = hs[j+2].x - hs[j].x;  gy4.y = hs[j+2].y - hs[j].y;
        gy4.z = hs[j+2].z - hs[j].z;  gy4.w = hs[j+2].w - hs[j].w;
        acc += fabsf(gx4.x) + fabsf(gx4.y) + fabsf(gx4.z) + fabsf(gx4.w)
             + fabsf(gy4.x) + fabsf(gy4.y) + fabsf(gy4.z) + fabsf(gy4.w);
    }

    float s = block_reduce(acc, red4);
    if (t == 0) {
        const int bid = (n * gridDim.y + ty) * gridDim.x + tx;
        part_pan[bid] = (double)s;
    }
}

__global__ __launch_bounds__(256)
void k3_final(const double* __restrict__ part_ms,
              const double* __restrict__ part_ref,
              const double* __restrict__ part_pan,
              int nb1, int nb2, float* __restrict__ outv)
{
    __shared__ double sMs[256], sRef[256], sPan[256];
    const int t = threadIdx.x;
    double a = 0.0, b = 0.0, c = 0.0;
    for (int i = t; i < nb1; i += 256) {
        a += part_ms[i];
        b += part_ref[i];
    }
    for (int i = t; i < nb2; i += 256) {
        c += part_pan[i];
    }
    sMs[t] = a; sRef[t] = b; sPan[t] = c;
    __syncthreads();
    for (int s = 128; s > 0; s >>= 1) {
        if (t < s) { sMs[t] += sMs[t + s]; sRef[t] += sRef[t + s]; sPan[t] += sPan[t + s]; }
        __syncthreads();
    }
    if (t == 0) {
        const double inv_big = 1.0 / (double)(N_ * C_ * H_ * W_);
        const double inv_pan = 1.0 / (double)(N_ * 1 * H_ * W_);
        double total = sMs[0] * inv_big + sRef[0] * inv_big + sPan[0] * inv_pan;
        outv[0] = (float)total;
    }
}

extern "C" void kernel_launch(void* const* d_in, const int* in_sizes, int n_in,
                              void* d_out, int out_size, void* d_ws, size_t ws_size,
                              hipStream_t stream) {
    const float* refp = (const float*)d_in[0];
    const float* pan  = (const float*)d_in[1];
    const float* msp  = (const float*)d_in[2];
    const float* outp = (const float*)d_in[3];

    const int NB1 = (W_ / TW) * (H_ / TH) * N_;   // 4*64*8 = 2048
    const int NB2 = NB1;

    char* ws = (char*)d_ws;
    float* o2p = (float*)ws;
    size_t o2p_bytes = (size_t)N_ * H_ * W_ * sizeof(float);
    double* part_ms  = (double*)(ws + o2p_bytes);
    double* part_ref = part_ms + NB1;
    double* part_pan = part_ref + NB1;

    dim3 grid(W_ / TW, H_ / TH, N_);
    k1_blur_sums<<<grid, THREADS, 0, stream>>>(outp, refp, msp, o2p, part_ms, part_ref);
    k2_sobel<<<grid, THREADS, 0, stream>>>(pan, o2p, part_pan);
    k3_final<<<1, 256, 0, stream>>>(part_ms, part_ref, part_pan, NB1, NB2, (float*)d_out);
}

// Round 7
// 176.511 us; speedup vs baseline: 1.2074x; 1.0111x over previous
//
#include <hip/hip_runtime.h>

// Problem geometry (fixed by setup_inputs)
constexpr int N_ = 8, C_ = 8, H_ = 1024, W_ = 1024;

// k1 tiling: 256x16 output tile, blur halo 2 -> 20 staged rows, SINGLE buffer
constexpr int TW = 256, TH = 16, R_ = 20;
constexpr int THREADS = 256;

// k2 tiling: 256x16, sobel halo 1 -> 18 staged rows
constexpr int R2_ = 18;

// Gaussian kernel: cv2.getGaussianKernel(5, 2), normalized
constexpr float G0_ = 0.15246914f;
constexpr float G1_ = 0.22184130f;
constexpr float G2_ = 0.25137912f;

#define GLOAD_LDS16(gp, lp) __builtin_amdgcn_global_load_lds( \
    (const __attribute__((address_space(1))) void*)(gp),      \
    (__attribute__((address_space(3))) void*)(lp), 16, 0, 0)
#define GLOAD_LDS4(gp, lp) __builtin_amdgcn_global_load_lds(  \
    (const __attribute__((address_space(1))) void*)(gp),      \
    (__attribute__((address_space(3))) void*)(lp), 4, 0, 0)

__device__ __forceinline__ float block_reduce(float v, float* red4) {
    #pragma unroll
    for (int off = 32; off > 0; off >>= 1) v += __shfl_down(v, off);
    const int lane = threadIdx.x & 63, wid = threadIdx.x >> 6;
    if (lane == 0) red4[wid] = v;
    __syncthreads();
    float s = 0.f;
    if (threadIdx.x == 0) s = red4[0] + red4[1] + red4[2] + red4[3];
    __syncthreads();
    return s;
}

// branchless reflect-101 for H=W=1024, arg range [-2, 1057]
__device__ __forceinline__ int refl(int y) {
    int a = (y < 0) ? -y : y;
    int b = 2046 - a;
    return (a < b) ? a : b;
}

__global__ __launch_bounds__(THREADS)
void k1_blur_sums(const float* __restrict__ outp,
                  const float* __restrict__ refp,
                  const float* __restrict__ msp,
                  float* __restrict__ o2p,
                  double* __restrict__ part_ms,
                  double* __restrict__ part_ref)
{
    __shared__ float til[R_ * TW];   // [20][256]; 1 row = 1 wave gload_lds16; 20KB
    __shared__ float hal[80];        // x-halo: [r][4] = cols {-2,-1,256,257}
    __shared__ float red4[4];

    const int t = threadIdx.x, lane = t & 63, wv = t >> 6;
    const int tx = blockIdx.x, ty = blockIdx.y, n = blockIdx.z;
    const int x0 = tx * TW, y0 = ty * TH;

    // thread strip: cols c0..c0+3, output rows sr0..sr0+3
    const int c0  = (t & 63) << 2;
    const int sr0 = (t >> 6) << 2;

    // stage channel c: interior = 5 full-row 1KB wave-loads; halo = 80 scalars
    auto stage = [&](int c) {
        const float* plane = outp + ((size_t)(n * C_ + c) << 20);
        #pragma unroll
        for (int k = 0; k < 5; ++k) {
            const int r = wv + (k << 2);               // rows wv, wv+4, ..., wv+16
            const int gy = refl(y0 + r - 2);
            GLOAD_LDS16(plane + ((size_t)gy << 10) + x0 + (lane << 2),
                        &til[r << 8]);
        }
        if (wv == 0 || (wv == 1 && lane < 16)) {       // 80 halo slots
            const int slot = (wv == 0) ? lane : (64 + lane);
            const int r = slot >> 2, cdx = slot & 3;
            const int gy = refl(y0 + r - 2);
            const int gx = refl(x0 + ((cdx < 2) ? cdx - 2 : cdx + 254));
            GLOAD_LDS4(plane + ((size_t)gy << 10) + gx,
                       &hal[(wv == 0) ? 0 : 64]);
        }
    };

    float accMs = 0.f, accRef = 0.f;
    float4 cs4[4] = {{0,0,0,0},{0,0,0,0},{0,0,0,0},{0,0,0,0}};

    for (int c = 0; c < C_; ++c) {
        stage(c);
        __syncthreads();   // drains stage (vmcnt0) -> til ready for all waves

        // rolling h-blur over 8 staged rows sr0..sr0+7
        float4 hh[8], ctr[4];
        #pragma unroll
        for (int k = 0; k < 8; ++k) {
            const int r = sr0 + k;                     // <= 19
            const float* rowp = til + (r << 8);
            float2 l2 = (c0 == 0)   ? *(const float2*)(hal + (r << 2))
                                    : *(const float2*)(rowp + c0 - 2);
            float4 m4 = *(const float4*)(rowp + c0);
            float2 r2 = (c0 == 252) ? *(const float2*)(hal + (r << 2) + 2)
                                    : *(const float2*)(rowp + c0 + 4);
            float4 h;
            h.x = G0_ * (l2.x + m4.z) + G1_ * (l2.y + m4.y) + G2_ * m4.x;
            h.y = G0_ * (l2.y + m4.w) + G1_ * (m4.x + m4.z) + G2_ * m4.y;
            h.z = G0_ * (m4.x + r2.x) + G1_ * (m4.y + m4.w) + G2_ * m4.z;
            h.w = G0_ * (m4.y + r2.y) + G1_ * (m4.z + r2.x) + G2_ * m4.w;
            hh[k] = h;
            if (k >= 2 && k <= 5) ctr[k - 2] = m4;     // raw out at output rows
        }

        // v-blur + losses, 4 output rows
        #pragma unroll
        for (int j = 0; j < 4; ++j) {
            float4 b;
            b.x = G0_*(hh[j].x+hh[j+4].x) + G1_*(hh[j+1].x+hh[j+3].x) + G2_*hh[j+2].x;
            b.y = G0_*(hh[j].y+hh[j+4].y) + G1_*(hh[j+1].y+hh[j+3].y) + G2_*hh[j+2].y;
            b.z = G0_*(hh[j].z+hh[j+4].z) + G1_*(hh[j+1].z+hh[j+3].z) + G2_*hh[j+2].z;
            b.w = G0_*(hh[j].w+hh[j+4].w) + G1_*(hh[j+1].w+hh[j+3].w) + G2_*hh[j+2].w;

            const size_t gidx = ((size_t)(n * C_ + c) * H_ + (y0 + sr0 + j)) * W_ + x0 + c0;
            float4 m = *(const float4*)(msp + gidx);
            float4 rr = *(const float4*)(refp + gidx);
            float4 o = ctr[j];

            accMs  += fabsf(b.x - m.x) + fabsf(b.y - m.y) + fabsf(b.z - m.z) + fabsf(b.w - m.w);
            accRef += fabsf(o.x - rr.x) + fabsf(o.y - rr.y) + fabsf(o.z - rr.z) + fabsf(o.w - rr.w);
            cs4[j].x += o.x; cs4[j].y += o.y; cs4[j].z += o.z; cs4[j].w += o.w;
        }

        __syncthreads();   // til reads done before next channel's stage overwrites
    }

    // out2pan write: 4 rows, 1KB contiguous per wave per row
    #pragma unroll
    for (int j = 0; j < 4; ++j) {
        const size_t oidx = ((size_t)n * H_ + (y0 + sr0 + j)) * W_ + x0 + c0;
        float4 w;
        w.x = cs4[j].x * 0.125f; w.y = cs4[j].y * 0.125f;
        w.z = cs4[j].z * 0.125f; w.w = cs4[j].w * 0.125f;
        *(float4*)&o2p[oidx] = w;
    }

    float sMs = block_reduce(accMs, red4);
    float sRef = block_reduce(accRef, red4);
    if (t == 0) {
        const int bid = (n * gridDim.y + ty) * gridDim.x + tx;
        part_ms[bid]  = (double)sMs;
        part_ref[bid] = (double)sRef;
    }
}

__global__ __launch_bounds__(THREADS)
void k2_sobel(const float* __restrict__ pan,
              const float* __restrict__ o2p,
              double* __restrict__ part_pan)
{
    __shared__ float d[R2_ * 256];   // staged rows = image rows y0-1 .. y0+16
    __shared__ float sd[R2_ * 2];    // side cols: [r][0]=x0-1, [r][1]=x0+256
    __shared__ float red4[4];

    const int t = threadIdx.x;
    const int tx = blockIdx.x, ty = blockIdx.y, n = blockIdx.z;
    const int x0 = tx * TW, y0 = ty * TH;
    const size_t base = (size_t)n * (H_ * W_);

    // interior staging: rows of 1KB (pan & o2p reads both contiguous per wave)
    for (int i = t; i < R2_ * 64; i += THREADS) {
        const int r = i >> 6, cf = (i & 63) << 2;
        const int gy = y0 + r - 1;
        float4 v = {0,0,0,0};
        if (gy >= 0 && gy < H_) {
            const size_t gi = base + ((size_t)gy << 10) + x0 + cf;
            float4 p4 = *(const float4*)(pan + gi);
            float4 q4 = *(const float4*)(o2p + gi);
            v.x = p4.x - q4.x; v.y = p4.y - q4.y; v.z = p4.z - q4.z; v.w = p4.w - q4.w;
        }
        *(float4*)&d[(r << 8) + cf] = v;
    }
    if (t < R2_ * 2) {
        const int r = t >> 1, s = t & 1;
        const int gy = y0 + r - 1;
        const int gx = s ? (x0 + 256) : (x0 - 1);
        float v = 0.f;
        if (gy >= 0 && gy < H_ && gx >= 0 && gx < W_) {
            const size_t gi = base + ((size_t)gy << 10) + gx;
            v = pan[gi] - o2p[gi];
        }
        sd[(r << 1) + s] = v;
    }
    __syncthreads();

    const int c0  = (t & 63) << 2;
    const int sr0 = (t >> 6) << 2;   // staged rows sr0..sr0+5; outputs sr0+1..sr0+4

    float4 hx[6], hs[6];
    #pragma unroll
    for (int k = 0; k < 6; ++k) {
        const int r = sr0 + k;                         // <= 17
        const float* rowp = d + (r << 8);
        float lft = (c0 == 0)   ? sd[r << 1]       : rowp[c0 - 1];
        float4 m4 = *(const float4*)(rowp + c0);
        float rgt = (c0 == 252) ? sd[(r << 1) + 1] : rowp[c0 + 4];
        hx[k].x = m4.y - lft;  hx[k].y = m4.z - m4.x;
        hx[k].z = m4.w - m4.y; hx[k].w = rgt - m4.z;
        hs[k].x = lft + 2.f*m4.x + m4.y;  hs[k].y = m4.x + 2.f*m4.y + m4.z;
        hs[k].z = m4.y + 2.f*m4.z + m4.w; hs[k].w = m4.z + 2.f*m4.w + rgt;
    }

    float acc = 0.f;
    #pragma unroll
    for (int j = 0; j < 4; ++j) {   // output centered at staged row sr0+j+1
        float4 gx4, gy4;
        gx4.x = hx[j].x + 2.f*hx[j+1].x + hx[j+2].x;
        gx4.y = hx[j].y + 2.f*hx[j+1].y + hx[j+2].y;
        gx4.z = hx[j].z + 2.f*hx[j+1].z + hx[j+2].z;
        gx4.w = hx[j].w + 2.f*hx[j+1].w + hx[j+2].w;
        gy4.x = hs[j+2].x - hs[j].x;  gy4.y = hs[j+2].y - hs[j].y;
        gy4.z = hs[j+2].z - hs[j].z;  gy4.w = hs[j+2].w - hs[j].w;
        acc += fabsf(gx4.x) + fabsf(gx4.y) + fabsf(gx4.z) + fabsf(gx4.w)
             + fabsf(gy4.x) + fabsf(gy4.y) + fabsf(gy4.z) + fabsf(gy4.w);
    }

    float s = block_reduce(acc, red4);
    if (t == 0) {
        const int bid = (n * gridDim.y + ty) * gridDim.x + tx;
        part_pan[bid] = (double)s;
    }
}

__global__ __launch_bounds__(256)
void k3_final(const double* __restrict__ part_ms,
              const double* __restrict__ part_ref,
              const double* __restrict__ part_pan,
              int nb1, int nb2, float* __restrict__ outv)
{
    __shared__ double sMs[256], sRef[256], sPan[256];
    const int t = threadIdx.x;
    double a = 0.0, b = 0.0, c = 0.0;
    for (int i = t; i < nb1; i += 256) {
        a += part_ms[i];
        b += part_ref[i];
    }
    for (int i = t; i < nb2; i += 256) {
        c += part_pan[i];
    }
    sMs[t] = a; sRef[t] = b; sPan[t] = c;
    __syncthreads();
    for (int s = 128; s > 0; s >>= 1) {
        if (t < s) { sMs[t] += sMs[t + s]; sRef[t] += sRef[t + s]; sPan[t] += sPan[t + s]; }
        __syncthreads();
    }
    if (t == 0) {
        const double inv_big = 1.0 / (double)(N_ * C_ * H_ * W_);
        const double inv_pan = 1.0 / (double)(N_ * 1 * H_ * W_);
        double total = sMs[0] * inv_big + sRef[0] * inv_big + sPan[0] * inv_pan;
        outv[0] = (float)total;
    }
}

extern "C" void kernel_launch(void* const* d_in, const int* in_sizes, int n_in,
                              void* d_out, int out_size, void* d_ws, size_t ws_size,
                              hipStream_t stream) {
    const float* refp = (const float*)d_in[0];
    const float* pan  = (const float*)d_in[1];
    const float* msp  = (const float*)d_in[2];
    const float* outp = (const float*)d_in[3];

    const int NB1 = (W_ / TW) * (H_ / TH) * N_;   // 4*64*8 = 2048
    const int NB2 = NB1;

    char* ws = (char*)d_ws;
    float* o2p = (float*)ws;
    size_t o2p_bytes = (size_t)N_ * H_ * W_ * sizeof(float);
    double* part_ms  = (double*)(ws + o2p_bytes);
    double* part_ref = part_ms + NB1;
    double* part_pan = part_ref + NB1;

    dim3 grid(W_ / TW, H_ / TH, N_);
    k1_blur_sums<<<grid, THREADS, 0, stream>>>(outp, refp, msp, o2p, part_ms, part_ref);
    k2_sobel<<<grid, THREADS, 0, stream>>>(pan, o2p, part_pan);
    k3_final<<<1, 256, 0, stream>>>(part_ms, part_ref, part_pan, NB1, NB2, (float*)d_out);
}